// Round 7
// baseline (131.275 us; speedup 1.0000x reference)
//
#include <hip/hip_runtime.h>
#include <math.h>

#define Bq 4
#define Cq 64
#define Hq 160
#define Wq 160
#define HWq (Hq*Wq)      // 25600
#define OUTq 64
#define KKq 576          // Cq*9
#define KS  18           // KKq/32
#define SROW 584         // padded kk row (fp16 units); 1168 B, rows 16B-aligned
#define HSTRIDE 72       // halo px stride (ushorts) = 144 B

typedef __attribute__((ext_vector_type(8))) _Float16 half8;
typedef __attribute__((ext_vector_type(2))) _Float16 half2v;
typedef __attribute__((ext_vector_type(4))) float float4v;
typedef __attribute__((ext_vector_type(4))) unsigned short ushort4v;
typedef unsigned short ushort_t;
typedef unsigned int uint_t;

__device__ __forceinline__ ushort_t f2h(float f) {          // RNE f32->f16
    return __builtin_bit_cast(ushort_t, (_Float16)f);
}
__device__ __forceinline__ uint_t f2hdup(float f) {         // (h,h) packed
    uint_t u = (uint_t)f2h(f);
    return u | (u << 16);
}
__device__ __forceinline__ half2v h2(uint_t u) {
    return __builtin_bit_cast(half2v, u);
}
#define MFMA16(a,b,c) __builtin_amdgcn_mfma_f32_16x16x32_f16((a),(b),(c),0,0,0)

// ---------------------------------------------------------------------------
// K_prep: x NCHW f32 -> xt NHWC fp16; weight prepack on first 216 blocks.
// ---------------------------------------------------------------------------
__global__ void __launch_bounds__(256) k_prep(const float* __restrict__ x,
                                              const float* __restrict__ dcn_w,
                                              const float* __restrict__ off_w,
                                              const float* __restrict__ msk_w,
                                              ushort_t* __restrict__ xt,
                                              ushort_t* __restrict__ wtf,
                                              ushort_t* __restrict__ cwf2) {
    __shared__ float tile[64][65];
    int b = blockIdx.y, hw0 = blockIdx.x * 64;
    int tid = threadIdx.x;
    int l16 = tid & 15, crow = tid >> 4;        // crow 0..15
#pragma unroll
    for (int i = 0; i < 4; ++i) {
        int c = crow + i*16;
        float4 v = *(const float4*)(x + ((size_t)(b*Cq + c))*HWq + hw0 + l16*4);
        tile[c][l16*4+0] = v.x;
        tile[c][l16*4+1] = v.y;
        tile[c][l16*4+2] = v.z;
        tile[c][l16*4+3] = v.w;
    }
    __syncthreads();
#pragma unroll
    for (int it = 0; it < 4; ++it) {
        int hw = (tid >> 4) + it*16;
        int c4 = (tid & 15) * 4;
        uint_t v0 = (uint_t)f2h(tile[c4+0][hw]) | ((uint_t)f2h(tile[c4+1][hw]) << 16);
        uint_t v1 = (uint_t)f2h(tile[c4+2][hw]) | ((uint_t)f2h(tile[c4+3][hw]) << 16);
        uint2 vv; vv.x = v0; vv.y = v1;
        *(uint2*)(xt + ((size_t)b*HWq + hw0 + hw)*64 + c4) = vv;
    }
    if (blockIdx.y == 0 && blockIdx.x < 216) {
        int id = blockIdx.x*256 + tid;
        if (id < 4*KS*512) {
            int j = id & 7, ln = (id>>3) & 63, ks = (id>>9) % KS, g = id/(512*KS);
            int kk = ks*32 + (ln>>4)*8 + j;
            int c  = kk & 63, kt = kk >> 6;
            int m  = g*16 + (ln&15);
            wtf[id] = f2h(dcn_w[m*KKq + c*9 + kt]);
        }
        int id2 = id - 4*KS*512;
        if (id2 >= 0 && id2 < 9*2*2*512) {
            int j = id2 & 7, ln = (id2>>3) & 63;
            int ks2 = (id2>>9) & 1, g = (id2>>10) & 1, k = id2 >> 11;
            int co = g*16 + (ln&15);
            int c  = ks2*32 + (ln>>4)*8 + j;
            float w = 0.f;
            if (co < 18)      w = off_w[co*KKq + c*9 + k];
            else if (co < 27) w = msk_w[(co-18)*KKq + c*9 + k];
            cwf2[id2] = f2h(w);
        }
    }
}

// ---------------------------------------------------------------------------
// K_fused: 2-ROW blocks (32 px, 512 threads, 8 waves). Per-wave phase shapes
// identical to the 16-px version; fixed per-block costs amortized over 2x px:
//  halo 4x18 rows (-33%/px), barriers/decode/af-hoist/a-rows (-50%/px).
//  Wave roles: conv w=(r2,kh,gM); Phase B h=w*2+halfi (16 half-waves x 18it);
//  Phase C w=(g,nt). Task id t = k*32 + r*16 + p (k tap, r row, p col).
//  + XCD swizzle (3200%8==0), ILP pipelines from r6 kept.
// LDS: s_s 32xSROW = 37,376 (union: halo 10,368 + s_part 8,192)
//    + s_A16 2,304 + s_W 4,608 = 44,288 B -> 3 blocks/CU = 24 waves/CU
//    (same residency as r6's measured occupancy).
// ---------------------------------------------------------------------------
__global__ void __launch_bounds__(512, 6) k_fused(const ushort_t* __restrict__ xt,
                                                  const ushort_t* __restrict__ cwf2,
                                                  const float* __restrict__ off_b,
                                                  const float* __restrict__ msk_b,
                                                  const ushort_t* __restrict__ wtf,
                                                  float* __restrict__ out) {
    __shared__ __align__(16) char s_mem[32*SROW*2];          // 37,376 B
    __shared__ __align__(16) ushort4v s_A16[288];            //  2,304 B
    __shared__ __align__(16) uint4 s_W[288];                 //  4,608 B
    ushort_t* halo   = (ushort_t*)s_mem;                     // [0, 10368)
    float*    s_part = (float*)(s_mem + 10368);              // [10368, 18560)
    ushort_t* s_s    = (ushort_t*)s_mem;                     // Phase B/C

    // XCD swizzle: 3200 blocks, contiguous 400-block chunk per XCD.
    int bid = blockIdx.x;
    int blk = (bid & 7) * 400 + (bid >> 3);
    int jt = blk % 10, ih = (blk/10) % 80, b = blk/800;
    int i = ih*2, j0 = jt*16;
    int tid = threadIdx.x, lane = tid & 63, w = tid >> 6;
    int n = lane & 15, quad = lane >> 4;

    // conv wave roles: w = r2*4 + kh*2 + gM
    int gM = w & 1, kh = (w >> 1) & 1, r2 = w >> 2;

    // ---- Conv A-fragments: hoisted loads (independent of halo) ----
    half8 af[9];
#pragma unroll
    for (int s = 0; s < 9; ++s) {
        int st = kh*9 + s;                // 0..17
        int k = st >> 1, ks2 = st & 1;
        af[s] = *(const half8*)(cwf2 + (size_t)(((k*2+gM)*2+ks2)*512 + lane*8));
    }

    // ---- Stage halo: 4 rows x 18 px x 64 ch fp16 (576 seg-tasks) ----
    const ushort_t* xtb = xt + (size_t)b*HWq*64;
    {
        int t = tid;
        {
            int seg = t >> 3, sub = t & 7;
            int hr = seg / 18, px = seg % 18;
            int y = i + hr - 1, xx = j0 + px - 1;
            uint4 v = {0u,0u,0u,0u};
            if ((unsigned)y < (unsigned)Hq && (unsigned)xx < (unsigned)Wq)
                v = *(const uint4*)(xtb + ((size_t)y*Wq + xx)*64 + sub*8);
            *(uint4*)(halo + (hr*18 + px)*HSTRIDE + sub*8) = v;
        }
        t = tid + 512;
        if (t < 576) {
            int seg = t >> 3, sub = t & 7;
            int hr = seg / 18, px = seg % 18;
            int y = i + hr - 1, xx = j0 + px - 1;
            uint4 v = {0u,0u,0u,0u};
            if ((unsigned)y < (unsigned)Hq && (unsigned)xx < (unsigned)Wq)
                v = *(const uint4*)(xtb + ((size_t)y*Wq + xx)*64 + sub*8);
            *(uint4*)(halo + (hr*18 + px)*HSTRIDE + sub*8) = v;
        }
    }
    __syncthreads();

    // ---- Offset/mask conv: wave (r2, gM, kh) over 9 K-steps ----
    {
        float4v cacc = {0.f,0.f,0.f,0.f};
#pragma unroll
        for (int s = 0; s < 9; ++s) {
            int st = kh*9 + s;            // 0..17
            int k = st >> 1, ks2 = st & 1;
            int ky = k/3, kx = k - (k/3)*3;
            half8 bf = *(const half8*)(halo + ((r2+ky)*18 + n + kx)*HSTRIDE + quad*8 + ks2*32);
            cacc = MFMA16(af[s], bf, cacc);
        }
        *(float4v*)(s_part + w*256 + lane*4) = cacc;
    }
    __syncthreads();

    // ---- Phase A: 288 tap descriptors, t = k*32 + r*16 + p ----
    if (tid < 288) {
        int p = tid & 15, r = (tid >> 4) & 1, k = tid >> 5;
        #define RD(co) (s_part[((r*4)     + ((co)>>4))*256 + ((((co)&15)>>2)*16 + p)*4 + ((co)&3)] + \
                        s_part[((r*4) + 2 + ((co)>>4))*256 + ((((co)&15)>>2)*16 + p)*4 + ((co)&3)])
        float oy = RD(2*k)   + off_b[2*k];
        float ox = RD(2*k+1) + off_b[2*k+1];
        float mv = RD(18+k)  + msk_b[k];
        #undef RD
        float m = 1.f/(1.f + __expf(-mv));
        float py = oy + (float)(i + r - 1 + k/3);
        float px = ox + (float)(j0 + p - 1 + (k - (k/3)*3));
        float fy = floorf(py), fx = floorf(px);
        int y0 = (int)fy, x0 = (int)fx;
        float wy1 = py - fy, wx1 = px - fx;
        float wy0 = 1.f - wy1, wx0 = 1.f - wx1;
        bool vy0 = (y0 >= 0) & (y0 < Hq),   vy1 = (y0+1 >= 0) & (y0+1 < Hq);
        bool vx0 = (x0 >= 0) & (x0 < Wq),   vx1 = (x0+1 >= 0) & (x0+1 < Wq);
        int yc0 = min(max(y0,   0), Hq-1), yc1 = min(max(y0+1, 0), Hq-1);
        int xc0 = min(max(x0,   0), Wq-1), xc1 = min(max(x0+1, 0), Wq-1);
        ushort4v av;
        av.x = (ushort_t)(yc0*Wq + xc0);
        av.y = (ushort_t)(yc0*Wq + xc1);
        av.z = (ushort_t)(yc1*Wq + xc0);
        av.w = (ushort_t)(yc1*Wq + xc1);
        s_A16[tid] = av;
        s_W[tid] = make_uint4(f2hdup((vy0 && vx0) ? wy0*wx0*m : 0.f),
                              f2hdup((vy0 && vx1) ? wy0*wx1*m : 0.f),
                              f2hdup((vy1 && vx0) ? wy1*wx0*m : 0.f),
                              f2hdup((vy1 && vx1) ? wy1*wx1*m : 0.f));
    }
    __syncthreads();

    // ---- Phase B: 16 half-waves x 18 iters, 1-deep pipelined ----
    {
        int lane4 = (lane & 31) * 4;
        int halfi = lane >> 5;
        const char* xtbB = (const char*)xtb;
        char* s_sb = (char*)s_s;
        int t = w*2 + halfi;                     // task for iter 0 (0..15)
        ushort4v A = s_A16[t];
        uint4 Wt   = s_W[t];
        uint_t u00 = *(const uint_t*)(xtbB + (((uint_t)A.x) << 7) + lane4);
        uint_t u01 = *(const uint_t*)(xtbB + (((uint_t)A.y) << 7) + lane4);
        uint_t u10 = *(const uint_t*)(xtbB + (((uint_t)A.z) << 7) + lane4);
        uint_t u11 = *(const uint_t*)(xtbB + (((uint_t)A.w) << 7) + lane4);
#pragma unroll
        for (int iter = 0; iter < 18; ++iter) {
            int t_cur = t;
            uint4 Wc = Wt;
            uint_t v00 = u00, v01 = u01, v10 = u10, v11 = u11;
            if (iter < 17) {                     // prefetch iter+1
                t += 16;
                A  = s_A16[t];
                Wt = s_W[t];
                u00 = *(const uint_t*)(xtbB + (((uint_t)A.x) << 7) + lane4);
                u01 = *(const uint_t*)(xtbB + (((uint_t)A.y) << 7) + lane4);
                u10 = *(const uint_t*)(xtbB + (((uint_t)A.z) << 7) + lane4);
                u11 = *(const uint_t*)(xtbB + (((uint_t)A.w) << 7) + lane4);
            }
            // t = k*32 + px: row px (0..31), col-block k (0..8)
            uint_t dst = (uint_t)((t_cur & 31)*(SROW*2) + (t_cur >> 5)*128);
            half2v acc2 = h2(v00) * h2(Wc.x);
            acc2 = __builtin_elementwise_fma(h2(v01), h2(Wc.y), acc2);
            acc2 = __builtin_elementwise_fma(h2(v10), h2(Wc.z), acc2);
            acc2 = __builtin_elementwise_fma(h2(v11), h2(Wc.w), acc2);
            *(uint_t*)(s_sb + dst + lane4) = __builtin_bit_cast(uint_t, acc2);
        }
    }
    __syncthreads();

    // ---- Phase C: wave (g = w>>1, nt = w&1) -> o rows [g*16,+16), row i+nt ----
    {
        int g = w >> 1, nt = w & 1;
        float4v acc = {0.f,0.f,0.f,0.f};
        const ushort_t* arow = wtf + ((size_t)(g*KS)*64 + lane)*8;
        const ushort_t* brow = s_s + (nt*16 + n)*SROW + quad*8;
        half8 a_cur = *(const half8*)(arow);
#pragma unroll
        for (int ks = 0; ks < KS; ++ks) {
            half8 a_next = a_cur;
            if (ks < KS-1) a_next = *(const half8*)(arow + (ks+1)*512);
            half8 bf = *(const half8*)(brow + ks*32);
            acc = MFMA16(a_cur, bf, acc);
            a_cur = a_next;
        }
#pragma unroll
        for (int rr = 0; rr < 4; ++rr) {
            int o = g*16 + quad*4 + rr;
            out[(((size_t)b*OUTq + o)*Hq + (i + nt))*Wq + j0 + n] = acc[rr];
        }
    }
}

// ---------------------------------------------------------------------------
extern "C" void kernel_launch(void* const* d_in, const int* in_sizes, int n_in,
                              void* d_out, int out_size, void* d_ws, size_t ws_size,
                              hipStream_t stream) {
    const float* x     = (const float*)d_in[0];
    const float* off_w = (const float*)d_in[1];
    const float* off_b = (const float*)d_in[2];
    const float* msk_w = (const float*)d_in[3];
    const float* msk_b = (const float*)d_in[4];
    const float* dcn_w = (const float*)d_in[5];
    float* out = (float*)d_out;

    char* ws = (char*)d_ws;
    ushort_t* xt   = (ushort_t*)ws;                  // 13,107,200 B
    ushort_t* wtf  = xt + (size_t)Bq*HWq*64;         //     73,728 B
    ushort_t* cwf2 = wtf + 4*KS*512;                 //     36,864 B

    hipLaunchKernelGGL(k_prep, dim3(HWq/64, Bq), dim3(256), 0, stream,
                       x, dcn_w, off_w, msk_w, xt, wtf, cwf2);
    hipLaunchKernelGGL(k_fused, dim3(Bq*Hq*10/2), dim3(512), 0, stream,
                       xt, cwf2, off_b, msk_b, wtf, out);
}

// Round 8
// 130.997 us; speedup vs baseline: 1.0021x; 1.0021x over previous
//
#include <hip/hip_runtime.h>
#include <math.h>

#define Bq 4
#define Cq 64
#define Hq 160
#define Wq 160
#define HWq (Hq*Wq)      // 25600
#define OUTq 64
#define KKq 576          // Cq*9
#define KS  18           // KKq/32
#define SROW 584         // padded kk row (fp16 units); 1168 B, rows 16B-aligned
#define HSTRIDE 72       // halo px stride (ushorts) = 144 B

typedef __attribute__((ext_vector_type(8))) _Float16 half8;
typedef __attribute__((ext_vector_type(2))) _Float16 half2v;
typedef __attribute__((ext_vector_type(4))) float float4v;
typedef unsigned short ushort_t;
typedef unsigned int uint_t;

__device__ __forceinline__ ushort_t f2h(float f) {          // RNE f32->f16
    return __builtin_bit_cast(ushort_t, (_Float16)f);
}
__device__ __forceinline__ uint_t f2hdup(float f) {         // (h,h) packed
    uint_t u = (uint_t)f2h(f);
    return u | (u << 16);
}
__device__ __forceinline__ half2v h2(uint_t u) {
    return __builtin_bit_cast(half2v, u);
}
#define MFMA16(a,b,c) __builtin_amdgcn_mfma_f32_16x16x32_f16((a),(b),(c),0,0,0)

// ---------------------------------------------------------------------------
// K_prep: x NCHW f32 -> xt NHWC fp16; weight prepack on first 216 blocks.
//  Vectorized: float4 global loads, uint2 (4-ch) packed stores.
//  tile[64][65]: stride-65 floats => all LDS accesses <=2-way (free).
// ---------------------------------------------------------------------------
__global__ void __launch_bounds__(256) k_prep(const float* __restrict__ x,
                                              const float* __restrict__ dcn_w,
                                              const float* __restrict__ off_w,
                                              const float* __restrict__ msk_w,
                                              ushort_t* __restrict__ xt,
                                              ushort_t* __restrict__ wtf,
                                              ushort_t* __restrict__ cwf2) {
    __shared__ float tile[64][65];
    int b = blockIdx.y, hw0 = blockIdx.x * 64;
    int tid = threadIdx.x;
    int l16 = tid & 15, crow = tid >> 4;        // crow 0..15
#pragma unroll
    for (int i = 0; i < 4; ++i) {
        int c = crow + i*16;
        float4 v = *(const float4*)(x + ((size_t)(b*Cq + c))*HWq + hw0 + l16*4);
        tile[c][l16*4+0] = v.x;
        tile[c][l16*4+1] = v.y;
        tile[c][l16*4+2] = v.z;
        tile[c][l16*4+3] = v.w;
    }
    __syncthreads();
#pragma unroll
    for (int it = 0; it < 4; ++it) {
        int hw = (tid >> 4) + it*16;
        int c4 = (tid & 15) * 4;
        uint_t v0 = (uint_t)f2h(tile[c4+0][hw]) | ((uint_t)f2h(tile[c4+1][hw]) << 16);
        uint_t v1 = (uint_t)f2h(tile[c4+2][hw]) | ((uint_t)f2h(tile[c4+3][hw]) << 16);
        uint2 vv; vv.x = v0; vv.y = v1;
        *(uint2*)(xt + ((size_t)b*HWq + hw0 + hw)*64 + c4) = vv;
    }
    if (blockIdx.y == 0 && blockIdx.x < 216) {
        int id = blockIdx.x*256 + tid;
        if (id < 4*KS*512) {
            int j = id & 7, ln = (id>>3) & 63, ks = (id>>9) % KS, g = id/(512*KS);
            int kk = ks*32 + (ln>>4)*8 + j;
            int c  = kk & 63, kt = kk >> 6;
            int m  = g*16 + (ln&15);
            wtf[id] = f2h(dcn_w[m*KKq + c*9 + kt]);
        }
        int id2 = id - 4*KS*512;
        if (id2 >= 0 && id2 < 9*2*2*512) {
            int j = id2 & 7, ln = (id2>>3) & 63;
            int ks2 = (id2>>9) & 1, g = (id2>>10) & 1, k = id2 >> 11;
            int co = g*16 + (ln&15);
            int c  = ks2*32 + (ln>>4)*8 + j;
            float w = 0.f;
            if (co < 18)      w = off_w[co*KKq + c*9 + k];
            else if (co < 27) w = msk_w[(co-18)*KKq + c*9 + k];
            cwf2[id2] = f2h(w);
        }
    }
}

// ---------------------------------------------------------------------------
// K_fused (r6 base reverted from 2-row r7) + Phase-B depth-3 pipeline:
//  - XCD swizzle (contiguous 800-block chunk per XCD) kept
//  - conv a-frags hoisted above halo barrier (r6) kept
//  - Phase A stores PRE-SHIFTED 32-bit byte offsets (no per-iter extracts
//    or shifts); task t = tb + 8*iter (tb in 0..7) makes desc-read and
//    s_s dst addresses = runtime-base + compile-time immediate
//  - Phase B: 3 tasks in flight (12 gathers outstanding) to cover ~200cy
//    L2 latency; statically-indexed rotation (full unroll, no scratch)
//  - Phase C 1-deep a-row prefetch (r6) kept
// LDS: union{halo(7776)+partials(4096) | s_s(18688)} + s_A(2304) + s_W(2304)
//    = 23,296 B -> 6 blocks/CU (6<->7 blocks proven perf-neutral r0/r3).
// ---------------------------------------------------------------------------
__global__ void __launch_bounds__(256, 6) k_fused(const ushort_t* __restrict__ xt,
                                                  const ushort_t* __restrict__ cwf2,
                                                  const float* __restrict__ off_b,
                                                  const float* __restrict__ msk_b,
                                                  const ushort_t* __restrict__ wtf,
                                                  float* __restrict__ out) {
    __shared__ __align__(16) char s_mem[16*SROW*2];          // 18,688 B
    __shared__ __align__(16) uint4 s_A[144];                 //  2,304 B
    __shared__ __align__(16) uint4 s_W[144];                 //  2,304 B
    ushort_t* halo   = (ushort_t*)s_mem;                     // [0, 7776)
    float*    s_part = (float*)(s_mem + 7776);               // [7776, 11872)
    ushort_t* s_s    = (ushort_t*)s_mem;                     // Phase B/C

    // XCD-aware swizzle: consecutive hardware wgids round-robin the 8 XCDs;
    // give each XCD a contiguous 800-block chunk of the logical raster order.
    int bid = blockIdx.x;                 // 6400 = 4 * 160 * 10
    int blk = (bid & 7) * 800 + (bid >> 3);
    int jt = blk % 10, i = (blk/10) % Hq, b = blk/(10*Hq);
    int j0 = jt*16;
    int tid = threadIdx.x, lane = tid & 63, grp = tid >> 6;
    int n = lane & 15, quad = lane >> 4;

    // ---- Conv A-fragments: hoisted loads (independent of halo) ----
    int gM = grp & 1, kh = grp >> 1;
    half8 af[9];
#pragma unroll
    for (int s = 0; s < 9; ++s) {
        int st = kh*9 + s;                // 0..17
        int k = st >> 1, ks2 = st & 1;
        af[s] = *(const half8*)(cwf2 + (size_t)(((k*2+gM)*2+ks2)*512 + lane*8));
    }

    // ---- Stage halo: 3 rows x 18 px x 64 ch fp16 ----
    const ushort_t* xtb = xt + (size_t)b*HWq*64;
#pragma unroll
    for (int t = tid; t < 432; t += 256) {
        int seg = t >> 3, sub = t & 7;
        int ky = seg / 18, px = seg % 18;
        int y = i + ky - 1, xx = j0 + px - 1;
        uint4 v = {0u,0u,0u,0u};
        if (y >= 0 && y < Hq && xx >= 0 && xx < Wq)
            v = *(const uint4*)(xtb + ((size_t)y*Wq + xx)*64 + sub*8);
        *(uint4*)(halo + (ky*18 + px)*HSTRIDE + sub*8) = v;
    }
    __syncthreads();

    // ---- Offset/mask conv: wave (gM, kh) over 9 K-steps each ----
    {
        float4v cacc = {0.f,0.f,0.f,0.f};
#pragma unroll
        for (int s = 0; s < 9; ++s) {
            int st = kh*9 + s;            // 0..17
            int k = st >> 1, ks2 = st & 1;
            int ky = k/3, kx = k - (k/3)*3;
            half8 bf = *(const half8*)(halo + (ky*18 + n + kx)*HSTRIDE + quad*8 + ks2*32);
            cacc = MFMA16(af[s], bf, cacc);
        }
        *(float4v*)(s_part + grp*256 + lane*4) = cacc;
    }
    __syncthreads();

    // ---- Phase A: tap descriptors from conv partials ----
    if (tid < 144) {
        int p = tid & 15, k = tid >> 4;
        #define RD(co) (s_part[(((co)>>4)*256)     + ((((co)&15)>>2)*16 + p)*4 + ((co)&3)] + \
                        s_part[(2 + ((co)>>4))*256 + ((((co)&15)>>2)*16 + p)*4 + ((co)&3)])
        float oy = RD(2*k)   + off_b[2*k];
        float ox = RD(2*k+1) + off_b[2*k+1];
        float mv = RD(18+k)  + msk_b[k];
        #undef RD
        float m = 1.f/(1.f + __expf(-mv));
        float py = oy + (float)(i - 1 + k/3);
        float px = ox + (float)(j0 + p - 1 + (k - (k/3)*3));
        float fy = floorf(py), fx = floorf(px);
        int y0 = (int)fy, x0 = (int)fx;
        float wy1 = py - fy, wx1 = px - fx;
        float wy0 = 1.f - wy1, wx0 = 1.f - wx1;
        bool vy0 = (y0 >= 0) & (y0 < Hq),   vy1 = (y0+1 >= 0) & (y0+1 < Hq);
        bool vx0 = (x0 >= 0) & (x0 < Wq),   vx1 = (x0+1 >= 0) & (x0+1 < Wq);
        int yc0 = min(max(y0,   0), Hq-1), yc1 = min(max(y0+1, 0), Hq-1);
        int xc0 = min(max(x0,   0), Wq-1), xc1 = min(max(x0+1, 0), Wq-1);
        s_A[tid] = make_uint4((uint_t)((yc0*Wq + xc0)*128),
                              (uint_t)((yc0*Wq + xc1)*128),
                              (uint_t)((yc1*Wq + xc0)*128),
                              (uint_t)((yc1*Wq + xc1)*128));
        s_W[tid] = make_uint4(f2hdup((vy0 && vx0) ? wy0*wx0*m : 0.f),
                              f2hdup((vy0 && vx1) ? wy0*wx1*m : 0.f),
                              f2hdup((vy1 && vx0) ? wy1*wx0*m : 0.f),
                              f2hdup((vy1 && vx1) ? wy1*wx1*m : 0.f));
    }
    __syncthreads();

    // ---- Phase B: half-wave per (p,tap), 2 ch/lane, DEPTH-3 pipelined ----
    {
        int lane4 = (lane & 31) * 4;
        int halfi = lane >> 5;
        const char* xtbB = (const char*)xtb;
        char* s_sb = (char*)s_s;
        int tb = grp*2 + halfi;                  // base task 0..7; t = tb + 8*iter
        uint4 Wd[3];
        uint_t u[3][4];
        // prologue: issue gathers for iters 0..2 (12 loads in flight)
#pragma unroll
        for (int q = 0; q < 3; ++q) {
            uint4 A = s_A[tb + q*8];
            Wd[q]   = s_W[tb + q*8];
            u[q][0] = *(const uint_t*)(xtbB + A.x + lane4);
            u[q][1] = *(const uint_t*)(xtbB + A.y + lane4);
            u[q][2] = *(const uint_t*)(xtbB + A.z + lane4);
            u[q][3] = *(const uint_t*)(xtbB + A.w + lane4);
        }
#pragma unroll
        for (int iter = 0; iter < 18; ++iter) {
            const int q = iter % 3;              // static after full unroll
            uint4 Wc = Wd[q];
            uint_t v0 = u[q][0], v1 = u[q][1], v2 = u[q][2], v3 = u[q][3];
            if (iter + 3 < 18) {                 // refill slot q with iter+3
                uint4 A = s_A[tb + (iter+3)*8];
                Wd[q]   = s_W[tb + (iter+3)*8];
                u[q][0] = *(const uint_t*)(xtbB + A.x + lane4);
                u[q][1] = *(const uint_t*)(xtbB + A.y + lane4);
                u[q][2] = *(const uint_t*)(xtbB + A.z + lane4);
                u[q][3] = *(const uint_t*)(xtbB + A.w + lane4);
            }
            // t = tb + 8*iter, tb<8: row = tb + 8*(iter&1), colblk = iter>>1
            uint_t dst = (uint_t)(tb*(SROW*2) + (iter & 1)*(8*SROW*2) + (iter >> 1)*128);
            half2v acc2 = h2(v0) * h2(Wc.x);
            acc2 = __builtin_elementwise_fma(h2(v1), h2(Wc.y), acc2);
            acc2 = __builtin_elementwise_fma(h2(v2), h2(Wc.z), acc2);
            acc2 = __builtin_elementwise_fma(h2(v3), h2(Wc.w), acc2);
            *(uint_t*)(s_sb + dst + lane4) = __builtin_bit_cast(uint_t, acc2);
        }
    }
    __syncthreads();

    // ---- Phase C: wave grp -> o rows [grp*16, +16), 16 pixels ----
    float4v acc = {0.f,0.f,0.f,0.f};
    const ushort_t* arow = wtf + ((size_t)(grp*KS)*64 + lane)*8;
    const ushort_t* brow = s_s + n*SROW + quad*8;
    half8 a_cur = *(const half8*)(arow);
#pragma unroll
    for (int ks = 0; ks < KS; ++ks) {
        half8 a_next = a_cur;
        if (ks < KS-1) a_next = *(const half8*)(arow + (ks+1)*512);
        half8 bf = *(const half8*)(brow + ks*32);
        acc = MFMA16(a_cur, bf, acc);
        a_cur = a_next;
    }

#pragma unroll
    for (int r = 0; r < 4; ++r) {
        int o = grp*16 + quad*4 + r;
        out[(((size_t)b*OUTq + o)*Hq + i)*Wq + j0 + n] = acc[r];
    }
}

// ---------------------------------------------------------------------------
extern "C" void kernel_launch(void* const* d_in, const int* in_sizes, int n_in,
                              void* d_out, int out_size, void* d_ws, size_t ws_size,
                              hipStream_t stream) {
    const float* x     = (const float*)d_in[0];
    const float* off_w = (const float*)d_in[1];
    const float* off_b = (const float*)d_in[2];
    const float* msk_w = (const float*)d_in[3];
    const float* msk_b = (const float*)d_in[4];
    const float* dcn_w = (const float*)d_in[5];
    float* out = (float*)d_out;

    char* ws = (char*)d_ws;
    ushort_t* xt   = (ushort_t*)ws;                  // 13,107,200 B
    ushort_t* wtf  = xt + (size_t)Bq*HWq*64;         //     73,728 B
    ushort_t* cwf2 = wtf + 4*KS*512;                 //     36,864 B

    hipLaunchKernelGGL(k_prep, dim3(HWq/64, Bq), dim3(256), 0, stream,
                       x, dcn_w, off_w, msk_w, xt, wtf, cwf2);
    hipLaunchKernelGGL(k_fused, dim3(Bq*Hq*10), dim3(256), 0, stream,
                       xt, cwf2, off_b, msk_b, wtf, out);
}